// Round 3
// baseline (3139.459 us; speedup 1.0000x reference)
//
#include <hip/hip_runtime.h>
#include <hip/hip_bf16.h>

// Problem constants
#define NB 1024      // batch
#define NT 120       // seq len
#define NE 50        // embed (x occupies k=0..49)
#define NH 300       // hidden (h occupies k=50..349)
#define KP 352       // padded K for MFMA (11 chunks of 32); W rows 350,351 = 0
#define KCH 11       // K chunks of 32
#define WCH 44       // KP/8 : bf16x8 chunks per W column
#define AST 360      // LDS A-row stride in bf16 (k=350..359 stay zero; preds tail-safe)
#define HP2 304      // padded gate-columns (19 tiles of 16)
#define NBLK 64      // blocks = 1024 rows / 16
#define NROWS 16     // batch rows per block

typedef __bf16 bf16_t;
typedef __bf16 bf16x8 __attribute__((ext_vector_type(8)));
typedef __bf16 bf16x2 __attribute__((ext_vector_type(2)));
typedef float f32x4 __attribute__((ext_vector_type(4)));

__device__ __forceinline__ float sigmoidf_(float x) { return 1.0f / (1.0f + __expf(-x)); }
__device__ __forceinline__ float tanhf_(float x) {
    // tanh(x) = 1 - 2/(exp(2x)+1)
    return 1.0f - 2.0f / (__expf(2.0f * x) + 1.0f);
}

// WpT[col][k], col = g*HP2 + hc: k<350 -> W[k][g*300+hc] (W is [x(50);h(300)] rows), else 0
__global__ void prep_w2(const float* __restrict__ W, bf16_t* __restrict__ Wp) {
    int gid = blockIdx.x * 256 + threadIdx.x;
    if (gid >= 4 * HP2 * KP) return;
    int k = gid % KP;
    int col = gid / KP;
    int g = col / HP2, hc = col % HP2;
    float v = (k < 350 && hc < NH) ? W[(long)k * 1200 + g * NH + hc] : 0.0f;
    Wp[gid] = (bf16_t)v;
}

// Ut[cls][c] = U[c][cls], padded to 304 cols with zeros
__global__ void prep_ut(const float* __restrict__ U, float* __restrict__ Ut) {
    int gid = blockIdx.x * 256 + threadIdx.x;
    if (gid >= 5 * HP2) return;
    int cls = gid / HP2, c = gid % HP2;
    Ut[gid] = (c < NH) ? U[c * 5 + cls] : 0.0f;
}

// Persistent LSTM: block owns 16 batch rows for all 120 steps.
// LDS ping-pong A-buffer row = [x_t(50) | h_{t-1}(300) | zeros(10)], c in VGPRs.
// Waves 0-2: 5 col-tiles x 4 gates; wave 3: 4 tiles + preds[t-1] + x_{t+1} staging.
__global__ void __launch_bounds__(256, 1) lstm_persist(
    const int* __restrict__ ids, const float* __restrict__ emb,
    const float* __restrict__ bl, const bf16_t* __restrict__ Wp,
    const float* __restrict__ Ut, const float* __restrict__ b2,
    float* __restrict__ out)
{
    __shared__ bf16_t Abuf[2][NROWS * AST];
    const int tid = threadIdx.x, blk = blockIdx.x;
    const int wave = tid >> 6, lane = tid & 63;
    const int m = lane & 15, quad = lane >> 4;
    const int row0 = blk * NROWS;

    // zero both LDS buffers (pads must be 0)
    {
        uint32_t* p = (uint32_t*)&Abuf[0][0];
        const int nw = 2 * NROWS * AST / 2;   // 11520 dwords
        for (int i = tid; i < nw; i += 256) p[i] = 0u;
    }
    __syncthreads();
    // stage x_0 into Abuf[0]
    {
        int r = tid >> 4;               // 0..15
        int c0 = (tid & 15) * 4;        // 0..60
        int id = ids[(row0 + r) * NT + 0];
        const float* er = emb + (long)id * NE;
#pragma unroll
        for (int j = 0; j < 4; ++j) {
            int c = c0 + j;
            if (c < NE) Abuf[0][r * AST + c] = (bf16_t)er[c];
        }
    }
    __syncthreads();

    const int tstart = wave * 5;                 // wave 3 -> 15
    const int tcount = (wave < 3) ? 5 : 4;

    int   colv[5]; bool cok[5]; int bb[5][4]; float bias[5][4]; float creg[5][4];
#pragma unroll
    for (int ti = 0; ti < 5; ++ti) {
        int col = (tstart + ti) * 16 + m;
        colv[ti] = col;
        cok[ti] = (col < NH) && (ti < tcount);
#pragma unroll
        for (int g = 0; g < 4; ++g) {
            bb[ti][g] = (ti < tcount) ? (g * HP2 + col) * WCH : 0;
            bias[ti][g] = cok[ti] ? bl[g * NH + col] : 0.f;
        }
#pragma unroll
        for (int r = 0; r < 4; ++r) creg[ti][r] = 0.f;
    }

    const bf16x8* Wv = (const bf16x8*)Wp;

    for (int t = 0; t < NT; ++t) {
        const bf16_t* Ac = &Abuf[t & 1][0];
        bf16_t* An = &Abuf[(t + 1) & 1][0];

        // A fragments: A[row=m][k=kk*32+quad*8 ..+7], shared by all waves
        bf16x8 af[KCH];
        const bf16_t* Arow = Ac + m * AST;
#pragma unroll
        for (int kk = 0; kk < KCH; ++kk)
            af[kk] = *(const bf16x8*)(Arow + kk * 32 + quad * 8);

#pragma unroll
        for (int ti = 0; ti < 5; ++ti) {
            if (ti < tcount) {
                f32x4 acc[4];
#pragma unroll
                for (int g = 0; g < 4; ++g) acc[g] = (f32x4){0.f, 0.f, 0.f, 0.f};
#pragma unroll
                for (int kk = 0; kk < KCH; ++kk) {
#pragma unroll
                    for (int g = 0; g < 4; ++g)
                        acc[g] = __builtin_amdgcn_mfma_f32_16x16x32_bf16(
                            af[kk], Wv[bb[ti][g] + kk * 4 + quad], acc[g], 0, 0, 0);
                }
                // C/D: col = lane&15, row = quad*4 + r  (verified in round-2 pass)
#pragma unroll
                for (int r = 0; r < 4; ++r) {
                    float zi = acc[0][r] + bias[ti][0];
                    float zj = acc[1][r] + bias[ti][1];
                    float zf = acc[2][r] + bias[ti][2];
                    float zo = acc[3][r] + bias[ti][3];
                    float cn = creg[ti][r] * sigmoidf_(zf + 1.0f)
                             + sigmoidf_(zi) * tanhf_(zj);
                    creg[ti][r] = cn;
                    float hn = tanhf_(cn) * sigmoidf_(zo);
                    if (cok[ti])
                        An[(quad * 4 + r) * AST + NE + colv[ti]] = (bf16_t)hn;
                }
            }
        }

        if (wave == 3) {
            int r = lane >> 2, p = lane & 3;
            // preds[t-1] from Ac's h region (stable this step)
            if (t >= 1) {
                const bf16_t* hrow = Ac + r * AST + NE;
                const float* u0 = Ut + p * HP2;
                const float* u4 = Ut + 4 * HP2;
                float s = 0.f, s4 = 0.f;
#pragma unroll 4
                for (int c = 0; c < HP2; c += 2) {
                    bf16x2 h2 = *(const bf16x2*)(hrow + c);
                    float h0 = (float)h2[0], h1 = (float)h2[1];
                    s  += h0 * u0[c] + h1 * u0[c + 1];
                    s4 += h0 * u4[c] + h1 * u4[c + 1];
                }
                float* op = out + (long)(t - 1) * (NB * 5) + (row0 + r) * 5;
                op[p] = s + b2[p];
                if (p == 0) op[4] = s4 + b2[4];
            }
            // stage x_{t+1} into An (x region free during step t)
            if (t + 1 < NT) {
                int id = ids[(row0 + r) * NT + (t + 1)];
                const float* er = emb + (long)id * NE;
                for (int c = p; c < NE; c += 4)
                    An[r * AST + c] = (bf16_t)er[c];
            }
        }
        __syncthreads();
    }

    // preds[NT-1] from Abuf[NT&1] (final barrier already passed)
    if (wave == 3) {
        const bf16_t* Ac = &Abuf[NT & 1][0];
        int r = lane >> 2, p = lane & 3;
        const bf16_t* hrow = Ac + r * AST + NE;
        const float* u0 = Ut + p * HP2;
        const float* u4 = Ut + 4 * HP2;
        float s = 0.f, s4 = 0.f;
#pragma unroll 4
        for (int c = 0; c < HP2; c += 2) {
            bf16x2 h2 = *(const bf16x2*)(hrow + c);
            float h0 = (float)h2[0], h1 = (float)h2[1];
            s  += h0 * u0[c] + h1 * u0[c + 1];
            s4 += h0 * u4[c] + h1 * u4[c + 1];
        }
        float* op = out + (long)(NT - 1) * (NB * 5) + (row0 + r) * 5;
        op[p] = s + b2[p];
        if (p == 0) op[4] = s4 + b2[4];
    }
}

extern "C" void kernel_launch(void* const* d_in, const int* in_sizes, int n_in,
                              void* d_out, int out_size, void* d_ws, size_t ws_size,
                              hipStream_t stream) {
    const int* ids   = (const int*)d_in[0];
    const float* emb = (const float*)d_in[1];
    const float* W   = (const float*)d_in[2];
    const float* bl  = (const float*)d_in[3];
    const float* U   = (const float*)d_in[4];
    const float* b2  = (const float*)d_in[5];
    float* out = (float*)d_out;

    char* ws = (char*)d_ws;
    bf16_t* Wp = (bf16_t*)ws;                 // 4*304*352*2 = 856,064 B
    float*  Ut = (float*)(ws + 856064);       // 5*304*4    =   6,080 B

    prep_w2<<<(4 * HP2 * KP + 255) / 256, 256, 0, stream>>>(W, Wp);
    prep_ut<<<(5 * HP2 + 255) / 256, 256, 0, stream>>>(U, Ut);
    lstm_persist<<<NBLK, 256, 0, stream>>>(ids, emb, bl, Wp, Ut, b2, out);
}